// Round 2
// 191.652 us; speedup vs baseline: 1.0317x; 1.0317x over previous
//
#include <hip/hip_runtime.h>
#include <math.h>

#define B_ROWS 262144
#define RPG 8                                 // row-groups (32 lanes each) per block
#define CHUNKS 8                              // row-group iterations per block
#define ROWS_PER_BLOCK (RPG * CHUNKS)         // 64
#define THREADS (RPG * 32)                    // 256
#define NBLOCKS (B_ROWS / ROWS_PER_BLOCK)     // 4096

// output layout (floats)
#define BARY_OFF 0
#define EV_OFF   ((size_t)B_ROWS * 128)
#define ET_OFF   ((size_t)B_ROWS * 129)
#define EB_OFF   ((size_t)B_ROWS * 130)
#define ISO_OFF  ((size_t)B_ROWS * 131)
#define LC_OFF   ((size_t)B_ROWS * 131 + 1)
#define DEC_OFF  ((size_t)B_ROWS * 131 + 2)

// native vector type usable with __builtin_nontemporal_store
typedef float f4 __attribute__((ext_vector_type(4)));

// guarded reciprocal-sqrt: finite large value for s==0 so 0 * rsq stays 0
// (reference computes q/(norm+1e-8) -> 0 for zero rows; text_bytes==0 makes
// t_atoms exactly 0 for ~1/256 of rows).
__device__ __forceinline__ float rsq_guard(float s) {
    return __builtin_amdgcn_rsqf(fmaxf(s, 1e-14f));
}

__device__ __forceinline__ float det4(const float* m) {
    float s0 = m[0]*m[5]  - m[1]*m[4];
    float s1 = m[0]*m[6]  - m[2]*m[4];
    float s2 = m[0]*m[7]  - m[3]*m[4];
    float s3 = m[1]*m[6]  - m[2]*m[5];
    float s4 = m[1]*m[7]  - m[3]*m[5];
    float s5 = m[2]*m[7]  - m[3]*m[6];
    float c5 = m[10]*m[15] - m[11]*m[14];
    float c4 = m[9]*m[15]  - m[11]*m[13];
    float c3 = m[9]*m[14]  - m[10]*m[13];
    float c2 = m[8]*m[15]  - m[11]*m[12];
    float c1 = m[8]*m[14]  - m[10]*m[12];
    float c0 = m[8]*m[13]  - m[9]*m[12];
    return s0*c5 - s1*c4 + s2*c3 + s3*c2 - s4*c1 + s5*c0;
}

__global__ __launch_bounds__(THREADS) void bridge_main(
    const float* __restrict__ vis, const int* __restrict__ txt,
    const float* __restrict__ Wv, const float* __restrict__ bv,
    const float* __restrict__ Wt, const float* __restrict__ bt,
    const float* __restrict__ Wd, const float* __restrict__ bd,
    float* __restrict__ out, int* __restrict__ blockCnt)
{
    // smat: det staging, wave-synchronous (producer+consumer in same wave).
    __shared__ float  smat[RPG][3][16];
    __shared__ float  sEta[3][ROWS_PER_BLOCK];   // staged eta streams
    __shared__ float2 sDec[ROWS_PER_BLOCK];      // staged decision pairs
    __shared__ int    spk[RPG];

    const int tid = threadIdx.x;
    const int r   = tid >> 5;   // row-group within block
    const int q   = tid & 31;   // quaternion index

    // weights hoisted into registers for all 8 chunks (all 16B-aligned)
    float wv[12];
    ((float4*)wv)[0] = ((const float4*)Wv)[3*q+0];
    ((float4*)wv)[1] = ((const float4*)Wv)[3*q+1];
    ((float4*)wv)[2] = ((const float4*)Wv)[3*q+2];
    const float4 bv4 = ((const float4*)bv)[q];
    const float4 wt4 = ((const float4*)Wt)[q];
    const float4 bt4 = ((const float4*)bt)[q];
    const float4 wd0 = ((const float4*)Wd)[q];
    const float4 wd1 = ((const float4*)Wd)[32 + q];
    const float  bd0 = bd[0], bd1 = bd[1];

    const size_t blockRow0 = (size_t)blockIdx.x * ROWS_PER_BLOCK;

    int pkSum = 0;
    size_t row = blockRow0 + r;
    // prologue loads for chunk 0
    float x0 = vis[row*3+0], x1 = vis[row*3+1], x2 = vis[row*3+2];
    float tx = (float)txt[row];

    #pragma unroll 1
    for (int c = 0; c < CHUNKS; ++c) {
        // software prefetch of next chunk's inputs (clamped to stay in-bounds)
        const size_t nrow = (c + 1 < CHUNKS) ? (row + RPG) : row;
        const float nx0 = vis[nrow*3+0];
        const float nx1 = vis[nrow*3+1];
        const float nx2 = vis[nrow*3+2];
        const float ntx = (float)txt[nrow];

        float v[4], t[4], b[4];
        v[0] = fmaf(x0, wv[0], fmaf(x1, wv[1],  fmaf(x2, wv[2],  bv4.x)));
        v[1] = fmaf(x0, wv[3], fmaf(x1, wv[4],  fmaf(x2, wv[5],  bv4.y)));
        v[2] = fmaf(x0, wv[6], fmaf(x1, wv[7],  fmaf(x2, wv[8],  bv4.z)));
        v[3] = fmaf(x0, wv[9], fmaf(x1, wv[10], fmaf(x2, wv[11], bv4.w)));
        t[0] = fmaf(tx, wt4.x, bt4.x);
        t[1] = fmaf(tx, wt4.y, bt4.y);
        t[2] = fmaf(tx, wt4.z, bt4.z);
        t[3] = fmaf(tx, wt4.w, bt4.w);

        // project_to_su2 (guarded hardware rsq)
        {
            const float fv = rsq_guard(v[0]*v[0]+v[1]*v[1]+v[2]*v[2]+v[3]*v[3]);
            const float ft = rsq_guard(t[0]*t[0]+t[1]*t[1]+t[2]*t[2]+t[3]*t[3]);
            #pragma unroll
            for (int j = 0; j < 4; ++j) { v[j] *= fv; t[j] *= ft; }
        }

        // Karcher mean of 2 points reduces exactly to normalize(v+t)
        #pragma unroll
        for (int j = 0; j < 4; ++j) b[j] = v[j] + t[j];
        {
            const float fb = rsq_guard(b[0]*b[0]+b[1]*b[1]+b[2]*b[2]+b[3]*b[3]);
            #pragma unroll
            for (int j = 0; j < 4; ++j) b[j] *= fb;
        }

        // barycenter store: 512B contiguous per row-group, nontemporal
        {
            f4 bb; bb.x = b[0]; bb.y = b[1]; bb.z = b[2]; bb.w = b[3];
            __builtin_nontemporal_store(bb, (f4*)(out + BARY_OFF + row * 128 + 4 * q));
        }

        // decision partials across the row's 32 lanes
        float p0 = b[0]*wd0.x + b[1]*wd0.y + b[2]*wd0.z + b[3]*wd0.w;
        float p1 = b[0]*wd1.x + b[1]*wd1.y + b[2]*wd1.z + b[3]*wd1.w;
        #pragma unroll
        for (int off = 16; off >= 1; off >>= 1) {
            p0 += __shfl_xor(p0, off, 32);
            p1 += __shfl_xor(p1, off, 32);
        }

        // stage sampled quaternions (q = 0,8,16,24) for the dets.
        // Producer and consumer lanes are in the SAME wave (row-group is a
        // half-wave); DS ops from one wave complete in order, so no
        // __syncthreads needed — wave_barrier only pins compiler ordering.
        if ((q & 7) == 0) {
            const int k = q >> 3;
            *(float4*)&smat[r][0][k*4] = make_float4(v[0], v[1], v[2], v[3]);
            *(float4*)&smat[r][1][k*4] = make_float4(t[0], t[1], t[2], t[3]);
            *(float4*)&smat[r][2][k*4] = make_float4(b[0], b[1], b[2], b[3]);
        }
        __builtin_amdgcn_wave_barrier();

        int e = 0;
        if (q < 3) {
            float m[16];
            const float4* mm = (const float4*)&smat[r][q][0];
            ((float4*)m)[0] = mm[0]; ((float4*)m)[1] = mm[1];
            ((float4*)m)[2] = mm[2]; ((float4*)m)[3] = mm[3];
            e = det4(m) < 0.0f ? 1 : 0;
            sEta[q][c * RPG + r] = (float)e;   // staged for coalesced dump
        }
        __builtin_amdgcn_wave_barrier();

        const int eV = __shfl(e, 0, 32);
        const int eT = __shfl(e, 1, 32);
        const int eB = __shfl(e, 2, 32);
        if (q == 0) pkSum += (eV ^ eB) | ((eT ^ eB) << 8) | ((eV ^ eT) << 16);
        if (q == 3) sDec[c * RPG + r] = make_float2(p0 + bd0, p1 + bd1);

        x0 = nx0; x1 = nx1; x2 = nx2; tx = ntx;
        row += RPG;
    }

    if (q == 0) spk[r] = pkSum;
    __syncthreads();

    if (tid == 0) {
        int s = 0;
        #pragma unroll
        for (int i = 0; i < RPG; ++i) s += spk[i];
        blockCnt[blockIdx.x] = s;   // fields <= 64, fit in bytes
    }

    // coalesced line-aligned dumps of the staged small streams:
    // etas: 3 waves x 256B contiguous; decision: 2 waves x 256B contiguous
    if (tid < 192) {
        const int s = tid >> 6, i = tid & 63;
        __builtin_nontemporal_store(sEta[s][i],
                                    out + (size_t)B_ROWS * (128 + s) + blockRow0 + i);
    }
    if (tid < 128) {
        __builtin_nontemporal_store(((const float*)sDec)[tid],
                                    out + DEC_OFF + blockRow0 * 2 + tid);
    }
}

__global__ __launch_bounds__(256) void bridge_finalize(
    const int* __restrict__ blockCnt, float* __restrict__ out)
{
    __shared__ int s0[4], s1[4], s2[4];
    const int tid = threadIdx.x;
    int c0 = 0, c1 = 0, c2 = 0;
    #pragma unroll
    for (int i = 0; i < NBLOCKS / 256; ++i) {      // 16 independent loads in flight
        const int p = blockCnt[i * 256 + tid];
        c0 += p & 255;
        c1 += (p >> 8) & 255;
        c2 += (p >> 16) & 255;
    }
    #pragma unroll
    for (int off = 32; off >= 1; off >>= 1) {
        c0 += __shfl_down(c0, off, 64);
        c1 += __shfl_down(c1, off, 64);
        c2 += __shfl_down(c2, off, 64);
    }
    if ((tid & 63) == 0) {
        const int w = tid >> 6;
        s0[w] = c0; s1[w] = c1; s2[w] = c2;
    }
    __syncthreads();
    if (tid == 0) {
        int t0 = 0, t1 = 0, t2 = 0;
        #pragma unroll
        for (int i = 0; i < 4; ++i) { t0 += s0[i]; t1 += s1[i]; t2 += s2[i]; }
        out[ISO_OFF] = sqrtf((float)t0) + sqrtf((float)t1);
        out[LC_OFF]  = (float)t2 / (float)B_ROWS;
    }
}

extern "C" void kernel_launch(void* const* d_in, const int* in_sizes, int n_in,
                              void* d_out, int out_size, void* d_ws, size_t ws_size,
                              hipStream_t stream) {
    const float* vis = (const float*)d_in[0];
    const int*   txt = (const int*)d_in[1];
    const float* Wv  = (const float*)d_in[2];
    const float* bv  = (const float*)d_in[3];
    const float* Wt  = (const float*)d_in[4];
    const float* bt  = (const float*)d_in[5];
    const float* Wd  = (const float*)d_in[6];
    const float* bd  = (const float*)d_in[7];
    float* out = (float*)d_out;
    int* blockCnt = (int*)d_ws;   // NBLOCKS ints = 16 KiB

    bridge_main<<<NBLOCKS, THREADS, 0, stream>>>(vis, txt, Wv, bv, Wt, bt, Wd, bd, out, blockCnt);
    bridge_finalize<<<1, 256, 0, stream>>>(blockCnt, out);
}